// Round 11
// baseline (271.526 us; speedup 1.0000x reference)
//
#include <hip/hip_runtime.h>
#include <hip/hip_bf16.h>

// Qwen3 attention block, bf16-MFMA pipeline, round 11.
// B=2 T=2048 HID=1536 H=12 HKV=2 D=128. All I/O fp32; internal compute bf16.

#define B_   2
#define T_   2048
#define HID_ 1536
#define H_   12
#define HKV_ 2
#define D_   128
#define GQ_  (H_ / HKV_)
#define NQKV_ 2048   // fused projection width: 1536 q + 256 k + 256 v
#define SCALE_ 0.08838834764831845f  // 1/sqrt(128), folded into Q at epilogue

typedef unsigned short u16;
typedef __attribute__((ext_vector_type(4))) float f32x4;
typedef __attribute__((ext_vector_type(8))) short bf16x8;
typedef __attribute__((ext_vector_type(4))) unsigned short u16x4;
typedef __attribute__((ext_vector_type(8))) unsigned short u16x8;

__device__ __forceinline__ u16 f2b(float f) {
  union { __hip_bfloat16 h; u16 u; } cv;
  cv.h = __float2bfloat16(f);   // RNE
  return cv.u;
}
__device__ __forceinline__ float b2f(u16 u) {
  union { float f; unsigned i; } cv;
  cv.i = ((unsigned)u) << 16;
  return cv.f;
}

// async global->LDS, 16B per lane; LDS dest = wave-uniform base + lane*16.
__device__ __forceinline__ void glds16(const u16* g, u16* l) {
  __builtin_amdgcn_global_load_lds((const __attribute__((address_space(1))) void*)g,
                                   (__attribute__((address_space(3))) void*)l, 16, 0, 0);
}

// ---------------- merged fp32 -> bf16 convert: hidden, qkv weights, o weight ----------------
#define NH4_ 1572864  // 4096*1536/4
#define NQ4_ 589824   // 1536*1536/4
#define NK4_ 98304    // 256*1536/4
__global__ __launch_bounds__(256) void cvt_inputs(const float* __restrict__ hidden,
                                                  const float* __restrict__ q_w,
                                                  const float* __restrict__ k_w,
                                                  const float* __restrict__ v_w,
                                                  const float* __restrict__ o_w,
                                                  u16* __restrict__ hidden_b,
                                                  u16* __restrict__ qkvw,
                                                  u16* __restrict__ owb) {
  int i = blockIdx.x * 256 + threadIdx.x;
  const int stride = gridDim.x * 256;
  const int nqkv = NQ4_ + 2 * NK4_;
  const int total = NH4_ + nqkv + NQ4_;
  for (; i < total; i += stride) {
    float4 v;
    u16x4* dst;
    if (i < NH4_) {
      v = reinterpret_cast<const float4*>(hidden)[i];
      dst = reinterpret_cast<u16x4*>(hidden_b) + i;
    } else {
      const int j = i - NH4_;
      if (j < nqkv) {
        if (j < NQ4_) v = reinterpret_cast<const float4*>(q_w)[j];
        else if (j < NQ4_ + NK4_) v = reinterpret_cast<const float4*>(k_w)[j - NQ4_];
        else v = reinterpret_cast<const float4*>(v_w)[j - NQ4_ - NK4_];
        dst = reinterpret_cast<u16x4*>(qkvw) + j;
      } else {
        v = reinterpret_cast<const float4*>(o_w)[j - nqkv];
        dst = reinterpret_cast<u16x4*>(owb) + (j - nqkv);
      }
    }
    u16x4 o = {f2b(v.x), f2b(v.y), f2b(v.z), f2b(v.w)};
    *dst = o;
  }
}

// ---------------- bf16 GEMM, 64x128 tile, BK=64, 2-phase dbuf: C = A * W^T (fp32) ----------------
// Grid (N/128, M/64) = 768 blocks for the o-gemm -> exactly 3 blocks/CU (balanced).
// 4 waves 2x2: wave covers 32 rows x 64 cols = acc[2][4]. LDS 48KB dbuf -> 3 blocks/CU.
__global__ __launch_bounds__(256) void gemm_bt(const u16* __restrict__ A,
                                               const u16* __restrict__ W,
                                               float* __restrict__ C,
                                               int M, int N, int K) {
  __shared__ __align__(16) u16 As[2][64 * 64];
  __shared__ __align__(16) u16 Ws[2][128 * 64];
  const int tid  = threadIdx.x;
  const int lane = tid & 63;
  const int wid  = tid >> 6;
  const int wr = wid >> 1, wc = wid & 1;
  const int l15 = lane & 15, kg = lane >> 4;
  const int rowBase = blockIdx.y * 64;
  const int colBase = blockIdx.x * 128;

  const int srow = lane >> 3;           // 0..7
  const int scol = (lane & 7) << 3;     // u16 col 0..56
  const u16* Ab = A + (size_t)(rowBase + wid * 16 + srow) * K + scol;   // 2 chunks: rows w*16..+16
  const u16* Wb = W + (size_t)(colBase + wid * 32 + srow) * K + scol;   // 4 chunks: rows w*32..+32

  const f32x4 zero4 = {0.f, 0.f, 0.f, 0.f};
  f32x4 acc[2][4];
#pragma unroll
  for (int m = 0; m < 2; ++m)
#pragma unroll
    for (int n = 0; n < 4; ++n) acc[m][n] = zero4;

  const int nt = K >> 6;
#pragma unroll
  for (int c = 0; c < 2; ++c)
    glds16(Ab + (size_t)(c * 8) * K, &As[0][(wid * 2 + c) * 512]);
#pragma unroll
  for (int c = 0; c < 4; ++c)
    glds16(Wb + (size_t)(c * 8) * K, &Ws[0][(wid * 4 + c) * 512]);
  asm volatile("s_waitcnt vmcnt(0)" ::: "memory");
  __builtin_amdgcn_s_barrier();
  asm volatile("" ::: "memory");
  int cur = 0;

  for (int t = 0; t < nt; ++t) {
    if (t + 1 < nt) {       // issue next tile's loads; latency hides under compute
      const int k0 = (t + 1) << 6;
#pragma unroll
      for (int c = 0; c < 2; ++c)
        glds16(Ab + (size_t)(c * 8) * K + k0, &As[cur ^ 1][(wid * 2 + c) * 512]);
#pragma unroll
      for (int c = 0; c < 4; ++c)
        glds16(Wb + (size_t)(c * 8) * K + k0, &Ws[cur ^ 1][(wid * 4 + c) * 512]);
    }
    bf16x8 a[2][2], b[4][2];
#pragma unroll
    for (int m = 0; m < 2; ++m)
#pragma unroll
      for (int ks = 0; ks < 2; ++ks)
        a[m][ks] = *reinterpret_cast<const bf16x8*>(
            &As[cur][(wr * 32 + m * 16 + l15) * 64 + ks * 32 + kg * 8]);
#pragma unroll
    for (int n = 0; n < 4; ++n)
#pragma unroll
      for (int ks = 0; ks < 2; ++ks)
        b[n][ks] = *reinterpret_cast<const bf16x8*>(
            &Ws[cur][(wc * 64 + n * 16 + l15) * 64 + ks * 32 + kg * 8]);
    __builtin_amdgcn_s_setprio(1);
#pragma unroll
    for (int m = 0; m < 2; ++m)
#pragma unroll
      for (int n = 0; n < 4; ++n)
#pragma unroll
        for (int ks = 0; ks < 2; ++ks)
          acc[m][n] = __builtin_amdgcn_mfma_f32_16x16x32_bf16(a[m][ks], b[n][ks],
                                                              acc[m][n], 0, 0, 0);
    __builtin_amdgcn_s_setprio(0);
    if (t + 1 < nt) {
      asm volatile("s_waitcnt vmcnt(0)" ::: "memory");  // next tile landed (this wave)
      __builtin_amdgcn_s_barrier();                     // all waves: landed + cur drained
      asm volatile("" ::: "memory");
      cur ^= 1;
    }
  }
#pragma unroll
  for (int m = 0; m < 2; ++m) {
    const int row0 = rowBase + wr * 32 + m * 16 + kg * 4;
#pragma unroll
    for (int n = 0; n < 4; ++n) {
      const int col = colBase + wc * 64 + n * 16 + l15;
#pragma unroll
      for (int r = 0; r < 4; ++r) C[(size_t)(row0 + r) * N + col] = acc[m][n][r];
    }
  }
}

// ---------------- fused QKV GEMM (2-phase dbuf) + RMSNorm + RoPE + V-transpose ----------------
__global__ __launch_bounds__(256) void gemm_qkv(
    const u16* __restrict__ A, const u16* __restrict__ W,
    const float* __restrict__ cosb, const float* __restrict__ sinb,
    const float* __restrict__ q_nw, const float* __restrict__ k_nw,
    u16* __restrict__ q_b, u16* __restrict__ k_b, u16* __restrict__ vt_b) {
  // layout: buf b: A at [b*16384, +8192), W at [b*16384+8192, +8192).
  // epilogue reuses [0, 17536) as 128x137 bf16 tile.
  __shared__ __align__(16) u16 smem[32768];
  const int tid  = threadIdx.x;
  const int lane = tid & 63;
  const int wid  = tid >> 6;
  const int wr = wid >> 1, wc = wid & 1;
  const int l15 = lane & 15, kg = lane >> 4;
  const int rowBase = blockIdx.y * 128;
  const int colBase = blockIdx.x * 128;
  const int K = HID_;

  const int srow = lane >> 3;
  const int scol = (lane & 7) << 3;
  const u16* Ab = A + (size_t)(rowBase + wid * 32 + srow) * K + scol;
  const u16* Wb = W + (size_t)(colBase + wid * 32 + srow) * K + scol;

  const f32x4 zero4 = {0.f, 0.f, 0.f, 0.f};
  f32x4 acc[4][4];
#pragma unroll
  for (int m = 0; m < 4; ++m)
#pragma unroll
    for (int n = 0; n < 4; ++n) acc[m][n] = zero4;

  const int nt = K >> 6;  // 24
#pragma unroll
  for (int c = 0; c < 4; ++c) {
    glds16(Ab + (size_t)(c * 8) * K, &smem[(wid * 4 + c) * 512]);
    glds16(Wb + (size_t)(c * 8) * K, &smem[8192 + (wid * 4 + c) * 512]);
  }
  asm volatile("s_waitcnt vmcnt(0)" ::: "memory");
  __builtin_amdgcn_s_barrier();
  asm volatile("" ::: "memory");
  int cur = 0;

  for (int t = 0; t < nt; ++t) {
    if (t + 1 < nt) {
      const int k0 = (t + 1) << 6;
      const int ob = (cur ^ 1) * 16384;
#pragma unroll
      for (int c = 0; c < 4; ++c) {
        glds16(Ab + (size_t)(c * 8) * K + k0, &smem[ob + (wid * 4 + c) * 512]);
        glds16(Wb + (size_t)(c * 8) * K + k0, &smem[ob + 8192 + (wid * 4 + c) * 512]);
      }
    }
    const int ib = cur * 16384;
    bf16x8 a[4][2], b[4][2];
#pragma unroll
    for (int m = 0; m < 4; ++m)
#pragma unroll
      for (int ks = 0; ks < 2; ++ks)
        a[m][ks] = *reinterpret_cast<const bf16x8*>(
            &smem[ib + (wr * 64 + m * 16 + l15) * 64 + ks * 32 + kg * 8]);
#pragma unroll
    for (int n = 0; n < 4; ++n)
#pragma unroll
      for (int ks = 0; ks < 2; ++ks)
        b[n][ks] = *reinterpret_cast<const bf16x8*>(
            &smem[ib + 8192 + (wc * 64 + n * 16 + l15) * 64 + ks * 32 + kg * 8]);
    __builtin_amdgcn_s_setprio(1);
#pragma unroll
    for (int m = 0; m < 4; ++m)
#pragma unroll
      for (int n = 0; n < 4; ++n)
#pragma unroll
        for (int ks = 0; ks < 2; ++ks)
          acc[m][n] = __builtin_amdgcn_mfma_f32_16x16x32_bf16(a[m][ks], b[n][ks],
                                                              acc[m][n], 0, 0, 0);
    __builtin_amdgcn_s_setprio(0);
    if (t + 1 < nt) {
      asm volatile("s_waitcnt vmcnt(0)" ::: "memory");
      __builtin_amdgcn_s_barrier();
      asm volatile("" ::: "memory");
      cur ^= 1;
    }
  }

  // ---- epilogue: acc -> LDS tile (bf16, stride 137), then norm/rope/transpose ----
  __syncthreads();  // all LDS reads retired before overwrite
#pragma unroll
  for (int m = 0; m < 4; ++m)
#pragma unroll
    for (int n = 0; n < 4; ++n)
#pragma unroll
      for (int r = 0; r < 4; ++r)
        smem[(wr * 64 + m * 16 + kg * 4 + r) * 137 + wc * 64 + n * 16 + l15] =
            f2b(acc[m][n][r]);
  __syncthreads();

  const int ct = blockIdx.x;
  const int b = rowBase >> 11;
  if (ct < 14) {
    const float* nw = (ct < 12) ? q_nw : k_nw;
    const float nwl = nw[lane], nwh = nw[lane + 64];
    const float sc = (ct < 12) ? SCALE_ : 1.0f;
    u16* dstbase = (ct < 12) ? (q_b + (size_t)(b * H_ + ct) * T_ * D_)
                             : (k_b + (size_t)(b * HKV_ + (ct - 12)) * T_ * D_);
    for (int i = 0; i < 32; ++i) {
      const int row = wid * 32 + i;
      const int tok = rowBase + row;
      const int t = tok & (T_ - 1);
      const float x1 = b2f(smem[row * 137 + lane]);
      const float x2 = b2f(smem[row * 137 + lane + 64]);
      float ss = x1 * x1 + x2 * x2;
#pragma unroll
      for (int msk = 32; msk >= 1; msk >>= 1) ss += __shfl_xor(ss, msk);
      const float rinv = rsqrtf(ss * (1.0f / D_) + 1e-6f);
      const float c1 = cosb[(size_t)tok * D_ + lane];
      const float c2 = cosb[(size_t)tok * D_ + lane + 64];
      const float s1 = sinb[(size_t)tok * D_ + lane];
      const float s2 = sinb[(size_t)tok * D_ + lane + 64];
      const float n1 = x1 * rinv * nwl, n2 = x2 * rinv * nwh;
      u16* dst = dstbase + (size_t)t * D_;
      dst[lane] = f2b((n1 * c1 - n2 * s1) * sc);
      dst[lane + 64] = f2b((n2 * c2 + n1 * s2) * sc);
    }
  } else {
    const int hv = ct - 14;
    // kappa^-1 of lane (t&63 == lane by construction: rowBase%64==0)
    const int tp = (lane & 32) | (((lane >> 2) & 3) << 3) | (((lane >> 4) & 1) << 2) |
                   (lane & 3);
    u16* vb = vt_b + (size_t)(b * HKV_ + hv) * D_ * T_;
    const int tb = rowBase & (T_ - 1);
    for (int it = 0; it < 64; ++it) {
      const int d = wid * 32 + (it >> 1), half = it & 1;
      const float x = b2f(smem[(half * 64 + lane) * 137 + d]);
      vb[(size_t)d * T_ + tb + half * 64 + tp] = f2b(x);
    }
  }
}

// ---------------- Flash attention: chunked work items, swapped-QK, kappa-V ----------------
// Round-6 structure (measured best) + launch_bounds(256,4): cap VGPR at 128 so
// 4 blocks/CU co-reside (LDS 32KB x 4 = 128KB < 160KB; was VGPR-capped at 3).
__constant__ int QT_ARR[40] = {15,15,15,15,14,14,11,11,11,10, 7, 7, 3,
                               14,14,13,13,13,13,12,12,10,10, 9, 9, 6, 6,
                               12,12, 9, 8, 8, 8, 5, 5, 2,
                                4, 4, 1, 0};
__constant__ int C_ARR[40]  = { 0, 1, 2, 3, 0, 1, 0, 1, 2, 0, 0, 1,-1,
                                2, 3, 0, 1, 2, 3, 0, 1, 1, 2, 0, 1, 0, 1,
                                2, 3, 2, 0, 1, 2, 0, 1,-1,
                                0, 1,-1,-1};
__device__ __forceinline__ int nc_of(int qt) { return (qt < 8) ? 2 : ((qt < 12) ? 3 : 4); }
__device__ __forceinline__ int mlbase_of(int qt) {
  return (qt < 8) ? 2 * (qt - 4) : ((qt < 12) ? 8 + 3 * (qt - 8) : 20 + 4 * (qt - 12));
}
__device__ __forceinline__ int pbase_of(int qt) {
  return (qt < 8) ? (qt - 4) : ((qt < 12) ? 4 + 2 * (qt - 8) : 12 + 3 * (qt - 12));
}

__global__ __launch_bounds__(256, 4) void attn_kernel(const u16* __restrict__ q_b,
                                                      const u16* __restrict__ k_b,
                                                      const u16* __restrict__ vt_b,
                                                      u16* __restrict__ aout,
                                                      u16* __restrict__ po0,
                                                      float2* __restrict__ ml) {
  __shared__ __align__(16) u16 Ks[64 * 128];
  __shared__ __align__(16) u16 Vs[128 * 64];
  const int id = blockIdx.x;        // 0..959, bh fastest
  const int item = id / 24;
  const int bh = id - item * 24;
  const int qt = QT_ARR[item];
  const int c = C_ARR[item];
  int kt0, ktend;
  bool partial;
  if (c < 0) {
    kt0 = 0; ktend = 2 * qt + 1; partial = false;
  } else {
    const int nt = 2 * qt + 2;
    const int nc = nc_of(qt);
    const int base = nt / nc, rem = nt - base * nc;
    kt0 = c * base + (c < rem ? c : rem);
    ktend = kt0 + base + (c < rem ? 1 : 0) - 1;
    partial = true;
  }
  const int b = bh / H_, h = bh - b * H_;
  const int kvh = h / GQ_;
  const int tid = threadIdx.x;
  const int w = tid >> 6, lane = tid & 63;
  const int l15 = lane & 15, kg = lane >> 4;
  const int qbase = qt * 128;

  const u16* Kb = k_b + (size_t)(b * HKV_ + kvh) * T_ * D_;
  const u16* Vb = vt_b + (size_t)(b * HKV_ + kvh) * D_ * T_;

  bf16x8 qf[2][4];
#pragma unroll
  for (int qb = 0; qb < 2; ++qb) {
    const u16* qrow =
        q_b + ((size_t)(b * H_ + h) * T_ + qbase + w * 32 + qb * 16 + l15) * D_;
#pragma unroll
    for (int s4 = 0; s4 < 4; ++s4)
      qf[qb][s4] = *reinterpret_cast<const bf16x8*>(qrow + s4 * 32 + kg * 8);
  }

  int kK[4], vK[4];
#pragma unroll
  for (int cc = 0; cc < 4; ++cc) {
    const int ch = w * 4 + cc;
    const int kr = ch * 4 + (lane >> 4);
    kK[cc] = kr * D_ + (((lane & 15) << 3) ^ ((kr & 7) << 3));
    const int dr = ch * 8 + (lane >> 3);
    vK[cc] = dr * T_ + (((lane & 7) << 3) ^ ((dr & 7) << 3));
  }
  const int xorv = (l15 & 7) << 3;

  const f32x4 zero4 = {0.f, 0.f, 0.f, 0.f};
  f32x4 o[2][8];
#pragma unroll
  for (int qb = 0; qb < 2; ++qb)
#pragma unroll
    for (int n = 0; n < 8; ++n) o[qb][n] = zero4;
  float m[2] = {0.f, 0.f};       // init 0: masked tiles give p=exp(-3e38)=0 safely
  float lsum[2] = {0.f, 0.f};

  for (int kt = kt0; kt <= ktend; ++kt) {
    __syncthreads();  // previous tile fully consumed (WAR)
    {
      const size_t kb = (size_t)kt * 64;
#pragma unroll
      for (int cc = 0; cc < 4; ++cc) {
        glds16(Kb + kb * D_ + kK[cc], &Ks[(w * 4 + cc) * 512]);
        glds16(Vb + kb + vK[cc], &Vs[(w * 4 + cc) * 512]);
      }
    }
    __syncthreads();  // vmcnt(0) drain: tile ready
    f32x4 sc[2][4];
#pragma unroll
    for (int qb = 0; qb < 2; ++qb)
#pragma unroll
      for (int n = 0; n < 4; ++n) sc[qb][n] = zero4;
    __builtin_amdgcn_s_setprio(1);
#pragma unroll
    for (int n = 0; n < 4; ++n)
#pragma unroll
      for (int s4 = 0; s4 < 4; ++s4) {
        const int koff = (n * 16 + l15) * 128 + ((s4 * 32 + kg * 8) ^ xorv);
        bf16x8 kf = *reinterpret_cast<const bf16x8*>(&Ks[koff]);
#pragma unroll
        for (int qb = 0; qb < 2; ++qb)
          sc[qb][n] = __builtin_amdgcn_mfma_f32_16x16x32_bf16(kf, qf[qb][s4],
                                                              sc[qb][n], 0, 0, 0);
      }
    __builtin_amdgcn_s_setprio(0);
    if (kt >= 2 * qt) {  // diagonal region: mask k > q
#pragma unroll
      for (int qb = 0; qb < 2; ++qb) {
        const int qg = w * 32 + qb * 16 + l15;
        const int kbb = (kt - 2 * qt) * 64;
#pragma unroll
        for (int n = 0; n < 4; ++n)
#pragma unroll
          for (int r = 0; r < 4; ++r)
            if (kbb + n * 16 + kg * 4 + r > qg) sc[qb][n][r] = -3e38f;
      }
    }
    float pm[2];
#pragma unroll
    for (int qb = 0; qb < 2; ++qb) {
      float v = sc[qb][0][0];
#pragma unroll
      for (int n = 0; n < 4; ++n)
#pragma unroll
        for (int r = 0; r < 4; ++r) v = fmaxf(v, sc[qb][n][r]);
      v = fmaxf(v, __shfl_xor(v, 16));
      v = fmaxf(v, __shfl_xor(v, 32));
      pm[qb] = v;
    }
    if (__any((pm[0] > m[0] + 8.f) | (pm[1] > m[1] + 8.f))) {
#pragma unroll
      for (int qb = 0; qb < 2; ++qb) {
        const float mn = fmaxf(m[qb], pm[qb]);
        const float al = __expf(m[qb] - mn);
        m[qb] = mn;
        lsum[qb] *= al;
        float alT[4];
#pragma unroll
        for (int r = 0; r < 4; ++r)
          alT[r] = __shfl(al, (lane & 48) | (kg * 4 + r));
#pragma unroll
        for (int n = 0; n < 8; ++n)
#pragma unroll
          for (int r = 0; r < 4; ++r) o[qb][n][r] *= alT[r];
      }
    }
#pragma unroll
    for (int qb = 0; qb < 2; ++qb) {
      float rs = 0.f;
#pragma unroll
      for (int n = 0; n < 4; ++n)
#pragma unroll
        for (int r = 0; r < 4; ++r) {
          const float p = __expf(sc[qb][n][r] - m[qb]);
          sc[qb][n][r] = p;
          rs += p;
        }
      rs += __shfl_xor(rs, 16);
      rs += __shfl_xor(rs, 32);
      lsum[qb] += rs;
    }
    bf16x8 pf[2][2];
#pragma unroll
    for (int qb = 0; qb < 2; ++qb)
#pragma unroll
      for (int ks = 0; ks < 2; ++ks)
#pragma unroll
        for (int r = 0; r < 4; ++r) {
          pf[qb][ks][r] = (short)f2b(sc[qb][2 * ks][r]);
          pf[qb][ks][r + 4] = (short)f2b(sc[qb][2 * ks + 1][r]);
        }
    __builtin_amdgcn_s_setprio(1);
#pragma unroll
    for (int n = 0; n < 8; ++n)
#pragma unroll
      for (int ks = 0; ks < 2; ++ks) {
        const int voff = (n * 16 + l15) * 64 + ((ks * 32 + kg * 8) ^ xorv);
        bf16x8 vf = *reinterpret_cast<const bf16x8*>(&Vs[voff]);
#pragma unroll
        for (int qb = 0; qb < 2; ++qb)
          o[qb][n] = __builtin_amdgcn_mfma_f32_16x16x32_bf16(pf[qb][ks], vf,
                                                             o[qb][n], 0, 0, 0);
      }
    __builtin_amdgcn_s_setprio(0);
  }

  // epilogue: o[qb][n][r] is O[q = qb*16+kg*4+r][d = n*16+l15]
  if (!partial) {
    float invT[2][4];
#pragma unroll
    for (int qb = 0; qb < 2; ++qb) {
      const float inv = 1.0f / lsum[qb];
#pragma unroll
      for (int r = 0; r < 4; ++r)
        invT[qb][r] = __shfl(inv, (lane & 48) | (kg * 4 + r));
    }
#pragma unroll
    for (int qb = 0; qb < 2; ++qb) {
      const int t0 = qbase + w * 32 + qb * 16 + kg * 4;
#pragma unroll
      for (int n = 0; n < 8; ++n)
#pragma unroll
        for (int r = 0; r < 4; ++r)
          aout[(size_t)(b * T_ + t0 + r) * (H_ * D_) + h * D_ + n * 16 + l15] =
              f2b(o[qb][n][r] * invT[qb][r]);
    }
  } else {
    const int mlslot = bh * 36 + mlbase_of(qt) + c;
    if (kg == 0) {
#pragma unroll
      for (int qb = 0; qb < 2; ++qb) {
        float2 v;
        v.x = m[qb];
        v.y = lsum[qb];
        ml[(size_t)mlslot * 128 + w * 32 + qb * 16 + l15] = v;
      }
    }
    if (c == 0) {  // unnormalized partial into this q-tile's aout slot
#pragma unroll
      for (int qb = 0; qb < 2; ++qb) {
        const int t0 = qbase + w * 32 + qb * 16 + kg * 4;
#pragma unroll
        for (int n = 0; n < 8; ++n)
#pragma unroll
          for (int r = 0; r < 4; ++r)
            aout[(size_t)(b * T_ + t0 + r) * (H_ * D_) + h * D_ + n * 16 + l15] =
                f2b(o[qb][n][r]);
      }
    } else {       // unnormalized partial into scratch
      const int pslot = bh * 24 + pbase_of(qt) + (c - 1);
#pragma unroll
      for (int qb = 0; qb < 2; ++qb) {
        const int row0 = w * 32 + qb * 16 + kg * 4;
#pragma unroll
        for (int n = 0; n < 8; ++n)
#pragma unroll
          for (int r = 0; r < 4; ++r)
            po0[((size_t)pslot * 128 + row0 + r) * 128 + n * 16 + l15] =
                f2b(o[qb][n][r]);
      }
    }
  }
}

// ---------------- combine chunked partials (qt >= 4) ----------------
__global__ __launch_bounds__(256) void combine_kernel(u16* __restrict__ aout,
                                                      const u16* __restrict__ po0,
                                                      const float2* __restrict__ ml) {
  const int qt = 4 + blockIdx.x;    // 4..15
  const int bh = blockIdx.y;        // 0..23
  const int nc = nc_of(qt);
  const int mlb = bh * 36 + mlbase_of(qt);
  const int pb = bh * 24 + pbase_of(qt);
  const int b = bh / H_, h = bh - b * H_;
  const int t0 = qt * 128;
  const int tid = threadIdx.x;
  const int row = tid >> 1;
  const int colc = (tid & 1) << 6;

  float ms[4], ls[4];
  float mm = -3e38f;
  for (int cc = 0; cc < nc; ++cc) {
    const float2 v = ml[(size_t)(mlb + cc) * 128 + row];
    ms[cc] = v.x; ls[cc] = v.y;
    mm = fmaxf(mm, v.x);
  }
  float lt = 0.f;
  float scl[4];
  for (int cc = 0; cc < nc; ++cc) {
    scl[cc] = __expf(ms[cc] - mm);
    lt += ls[cc] * scl[cc];
  }
  const float inv = 1.0f / lt;
  for (int cc = 0; cc < nc; ++cc) scl[cc] *= inv;

  u16* a = aout + (size_t)(b * T_ + t0 + row) * (H_ * D_) + h * D_ + colc;
#pragma unroll
  for (int j = 0; j < 8; ++j) {
    u16x8 v0 = *reinterpret_cast<const u16x8*>(a + j * 8);
    float acc[8];
#pragma unroll
    for (int e = 0; e < 8; ++e) acc[e] = b2f(v0[e]) * scl[0];
    for (int cc = 1; cc < nc; ++cc) {
      const u16* p = po0 + ((size_t)(pb + cc - 1) * 128 + row) * 128 + colc;
      u16x8 vc = *reinterpret_cast<const u16x8*>(p + j * 8);
#pragma unroll
      for (int e = 0; e < 8; ++e) acc[e] += b2f(vc[e]) * scl[cc];
    }
    u16x8 outv;
#pragma unroll
    for (int e = 0; e < 8; ++e) outv[e] = f2b(acc[e]);
    *reinterpret_cast<u16x8*>(a + j * 8) = outv;
  }
}

extern "C" void kernel_launch(void* const* d_in, const int* in_sizes, int n_in,
                              void* d_out, int out_size, void* d_ws, size_t ws_size,
                              hipStream_t stream) {
  const float* hidden = (const float*)d_in[0];
  const float* cosb   = (const float*)d_in[1];
  const float* sinb   = (const float*)d_in[2];
  // d_in[3] = attention_mask (pure causal; implemented analytically)
  const float* q_w  = (const float*)d_in[4];
  const float* k_w  = (const float*)d_in[5];
  const float* v_w  = (const float*)d_in[6];
  const float* o_w  = (const float*)d_in[7];
  const float* q_nw = (const float*)d_in[8];
  const float* k_nw = (const float*)d_in[9];
  float* out = (float*)d_out;

  // ws (36MB):
  //   hidden_b [0,12)   phase 1 (dead after gemm_qkv) -> aout [0,12) phase 2
  //   qkvw     [12,18)  phase 1 (dead after gemm_qkv) -> ml [12,13) phase 2
  //   q_b      [18,30)  phase 1+2
  //   owb      [30,34.5) written by cvt_inputs, read by final o-gemm
  // d_out (24MB): k_b [19,21) + vt_b [21,23) (written by gemm_qkv, read by attn);
  //   po0 [0,18.87) attn partials; all overwritten by final o-gemm's fp32 out.
  char* ws = (char*)d_ws;
  const size_t MB = 1u << 20;
  u16*    hidden_b = (u16*)(ws);                   // [0,12)  phase 1
  u16*    qkvw     = (u16*)(ws + 12 * MB);         // [12,18) phase 1
  u16*    q_b      = (u16*)(ws + 18 * MB);         // [18,30)
  u16*    owb      = (u16*)(ws + 30 * MB);         // [30,34.5)
  u16*    aout     = (u16*)(ws);                   // [0,12)  phase 2
  float2* ml       = (float2*)(ws + 12 * MB);      // [12,13) phase 2
  u16*    k_b      = (u16*)((char*)d_out + 19 * MB);  // [19,21) of d_out
  u16*    vt_b     = (u16*)((char*)d_out + 21 * MB);  // [21,23) of d_out
  u16*    po0      = (u16*)d_out;                  // [0,18.87) of d_out

  const dim3 blk(256);
  const int M = B_ * T_;  // 4096

  // merged input converts (hidden, qkv weights, o weight)
  cvt_inputs<<<2048, blk, 0, stream>>>(hidden, q_w, k_w, v_w, o_w,
                                       hidden_b, qkvw, owb);

  // fused QKV projection + RMSNorm + RoPE + V-transpose
  gemm_qkv<<<dim3(NQKV_ / 128, M / 128), blk, 0, stream>>>(
      hidden_b, qkvw, cosb, sinb, q_nw, k_nw, q_b, k_b, vt_b);

  attn_kernel<<<960, blk, 0, stream>>>(q_b, k_b, vt_b, aout, po0, ml);
  combine_kernel<<<dim3(12, B_ * H_), blk, 0, stream>>>(aout, po0, ml);

  // o-projection: 64x128 tile -> 768 blocks = exactly 3/CU (balanced)
  gemm_bt<<<dim3(HID_ / 128, M / 64), blk, 0, stream>>>(aout, owb, out,
                                                        M, HID_, HID_);
}

// Round 12
// 181.612 us; speedup vs baseline: 1.4951x; 1.4951x over previous
//
#include <hip/hip_runtime.h>
#include <hip/hip_bf16.h>

// Qwen3 attention block, bf16-MFMA pipeline, round 12.
// B=2 T=2048 HID=1536 H=12 HKV=2 D=128. All I/O fp32; internal compute bf16.

#define B_   2
#define T_   2048
#define HID_ 1536
#define H_   12
#define HKV_ 2
#define D_   128
#define GQ_  (H_ / HKV_)
#define NQKV_ 2048   // fused projection width: 1536 q + 256 k + 256 v
#define SCALE_ 0.08838834764831845f  // 1/sqrt(128), folded into Q at epilogue

typedef unsigned short u16;
typedef __attribute__((ext_vector_type(4))) float f32x4;
typedef __attribute__((ext_vector_type(8))) short bf16x8;
typedef __attribute__((ext_vector_type(4))) unsigned short u16x4;
typedef __attribute__((ext_vector_type(8))) unsigned short u16x8;

__device__ __forceinline__ u16 f2b(float f) {
  union { __hip_bfloat16 h; u16 u; } cv;
  cv.h = __float2bfloat16(f);   // RNE
  return cv.u;
}
__device__ __forceinline__ float b2f(u16 u) {
  union { float f; unsigned i; } cv;
  cv.i = ((unsigned)u) << 16;
  return cv.f;
}

// async global->LDS, 16B per lane; LDS dest = wave-uniform base + lane*16.
__device__ __forceinline__ void glds16(const u16* g, u16* l) {
  __builtin_amdgcn_global_load_lds((const __attribute__((address_space(1))) void*)g,
                                   (__attribute__((address_space(3))) void*)l, 16, 0, 0);
}

// ---------------- merged fp32 -> bf16 convert: hidden, qkv weights, o weight ----------------
#define NH4_ 1572864  // 4096*1536/4
#define NQ4_ 589824   // 1536*1536/4
#define NK4_ 98304    // 256*1536/4
__global__ __launch_bounds__(256) void cvt_inputs(const float* __restrict__ hidden,
                                                  const float* __restrict__ q_w,
                                                  const float* __restrict__ k_w,
                                                  const float* __restrict__ v_w,
                                                  const float* __restrict__ o_w,
                                                  u16* __restrict__ hidden_b,
                                                  u16* __restrict__ qkvw,
                                                  u16* __restrict__ owb) {
  int i = blockIdx.x * 256 + threadIdx.x;
  const int stride = gridDim.x * 256;
  const int nqkv = NQ4_ + 2 * NK4_;
  const int total = NH4_ + nqkv + NQ4_;
  for (; i < total; i += stride) {
    float4 v;
    u16x4* dst;
    if (i < NH4_) {
      v = reinterpret_cast<const float4*>(hidden)[i];
      dst = reinterpret_cast<u16x4*>(hidden_b) + i;
    } else {
      const int j = i - NH4_;
      if (j < nqkv) {
        if (j < NQ4_) v = reinterpret_cast<const float4*>(q_w)[j];
        else if (j < NQ4_ + NK4_) v = reinterpret_cast<const float4*>(k_w)[j - NQ4_];
        else v = reinterpret_cast<const float4*>(v_w)[j - NQ4_ - NK4_];
        dst = reinterpret_cast<u16x4*>(qkvw) + j;
      } else {
        v = reinterpret_cast<const float4*>(o_w)[j - nqkv];
        dst = reinterpret_cast<u16x4*>(owb) + (j - nqkv);
      }
    }
    u16x4 o = {f2b(v.x), f2b(v.y), f2b(v.z), f2b(v.w)};
    *dst = o;
  }
}

// ---------------- bf16 GEMM, 64x128 tile, BK=64, 2-phase dbuf: C = A * W^T (fp32) ----------------
// Grid (N/128, M/64) = 768 blocks for the o-gemm -> exactly 3 blocks/CU (balanced).
__global__ __launch_bounds__(256) void gemm_bt(const u16* __restrict__ A,
                                               const u16* __restrict__ W,
                                               float* __restrict__ C,
                                               int M, int N, int K) {
  __shared__ __align__(16) u16 As[2][64 * 64];
  __shared__ __align__(16) u16 Ws[2][128 * 64];
  const int tid  = threadIdx.x;
  const int lane = tid & 63;
  const int wid  = tid >> 6;
  const int wr = wid >> 1, wc = wid & 1;
  const int l15 = lane & 15, kg = lane >> 4;
  const int rowBase = blockIdx.y * 64;
  const int colBase = blockIdx.x * 128;

  const int srow = lane >> 3;           // 0..7
  const int scol = (lane & 7) << 3;     // u16 col 0..56
  const u16* Ab = A + (size_t)(rowBase + wid * 16 + srow) * K + scol;   // 2 chunks
  const u16* Wb = W + (size_t)(colBase + wid * 32 + srow) * K + scol;   // 4 chunks

  const f32x4 zero4 = {0.f, 0.f, 0.f, 0.f};
  f32x4 acc[2][4];
#pragma unroll
  for (int m = 0; m < 2; ++m)
#pragma unroll
    for (int n = 0; n < 4; ++n) acc[m][n] = zero4;

  const int nt = K >> 6;
#pragma unroll
  for (int c = 0; c < 2; ++c)
    glds16(Ab + (size_t)(c * 8) * K, &As[0][(wid * 2 + c) * 512]);
#pragma unroll
  for (int c = 0; c < 4; ++c)
    glds16(Wb + (size_t)(c * 8) * K, &Ws[0][(wid * 4 + c) * 512]);
  asm volatile("s_waitcnt vmcnt(0)" ::: "memory");
  __builtin_amdgcn_s_barrier();
  asm volatile("" ::: "memory");
  int cur = 0;

  for (int t = 0; t < nt; ++t) {
    if (t + 1 < nt) {       // issue next tile's loads; latency hides under compute
      const int k0 = (t + 1) << 6;
#pragma unroll
      for (int c = 0; c < 2; ++c)
        glds16(Ab + (size_t)(c * 8) * K + k0, &As[cur ^ 1][(wid * 2 + c) * 512]);
#pragma unroll
      for (int c = 0; c < 4; ++c)
        glds16(Wb + (size_t)(c * 8) * K + k0, &Ws[cur ^ 1][(wid * 4 + c) * 512]);
    }
    bf16x8 a[2][2], b[4][2];
#pragma unroll
    for (int m = 0; m < 2; ++m)
#pragma unroll
      for (int ks = 0; ks < 2; ++ks)
        a[m][ks] = *reinterpret_cast<const bf16x8*>(
            &As[cur][(wr * 32 + m * 16 + l15) * 64 + ks * 32 + kg * 8]);
#pragma unroll
    for (int n = 0; n < 4; ++n)
#pragma unroll
      for (int ks = 0; ks < 2; ++ks)
        b[n][ks] = *reinterpret_cast<const bf16x8*>(
            &Ws[cur][(wc * 64 + n * 16 + l15) * 64 + ks * 32 + kg * 8]);
    __builtin_amdgcn_s_setprio(1);
#pragma unroll
    for (int m = 0; m < 2; ++m)
#pragma unroll
      for (int n = 0; n < 4; ++n)
#pragma unroll
        for (int ks = 0; ks < 2; ++ks)
          acc[m][n] = __builtin_amdgcn_mfma_f32_16x16x32_bf16(a[m][ks], b[n][ks],
                                                              acc[m][n], 0, 0, 0);
    __builtin_amdgcn_s_setprio(0);
    if (t + 1 < nt) {
      asm volatile("s_waitcnt vmcnt(0)" ::: "memory");  // next tile landed (this wave)
      __builtin_amdgcn_s_barrier();                     // all waves: landed + cur drained
      asm volatile("" ::: "memory");
      cur ^= 1;
    }
  }
#pragma unroll
  for (int m = 0; m < 2; ++m) {
    const int row0 = rowBase + wr * 32 + m * 16 + kg * 4;
#pragma unroll
    for (int n = 0; n < 4; ++n) {
      const int col = colBase + wc * 64 + n * 16 + l15;
#pragma unroll
      for (int r = 0; r < 4; ++r) C[(size_t)(row0 + r) * N + col] = acc[m][n][r];
    }
  }
}

// ---------------- fused QKV GEMM (2-phase dbuf) + RMSNorm + RoPE + V-transpose ----------------
__global__ __launch_bounds__(256) void gemm_qkv(
    const u16* __restrict__ A, const u16* __restrict__ W,
    const float* __restrict__ cosb, const float* __restrict__ sinb,
    const float* __restrict__ q_nw, const float* __restrict__ k_nw,
    u16* __restrict__ q_b, u16* __restrict__ k_b, u16* __restrict__ vt_b) {
  // layout: buf b: A at [b*16384, +8192), W at [b*16384+8192, +8192).
  // epilogue reuses [0, 17536) as 128x137 bf16 tile.
  __shared__ __align__(16) u16 smem[32768];
  const int tid  = threadIdx.x;
  const int lane = tid & 63;
  const int wid  = tid >> 6;
  const int wr = wid >> 1, wc = wid & 1;
  const int l15 = lane & 15, kg = lane >> 4;
  const int rowBase = blockIdx.y * 128;
  const int colBase = blockIdx.x * 128;
  const int K = HID_;

  const int srow = lane >> 3;
  const int scol = (lane & 7) << 3;
  const u16* Ab = A + (size_t)(rowBase + wid * 32 + srow) * K + scol;
  const u16* Wb = W + (size_t)(colBase + wid * 32 + srow) * K + scol;

  const f32x4 zero4 = {0.f, 0.f, 0.f, 0.f};
  f32x4 acc[4][4];
#pragma unroll
  for (int m = 0; m < 4; ++m)
#pragma unroll
    for (int n = 0; n < 4; ++n) acc[m][n] = zero4;

  const int nt = K >> 6;  // 24
#pragma unroll
  for (int c = 0; c < 4; ++c) {
    glds16(Ab + (size_t)(c * 8) * K, &smem[(wid * 4 + c) * 512]);
    glds16(Wb + (size_t)(c * 8) * K, &smem[8192 + (wid * 4 + c) * 512]);
  }
  asm volatile("s_waitcnt vmcnt(0)" ::: "memory");
  __builtin_amdgcn_s_barrier();
  asm volatile("" ::: "memory");
  int cur = 0;

  for (int t = 0; t < nt; ++t) {
    if (t + 1 < nt) {
      const int k0 = (t + 1) << 6;
      const int ob = (cur ^ 1) * 16384;
#pragma unroll
      for (int c = 0; c < 4; ++c) {
        glds16(Ab + (size_t)(c * 8) * K + k0, &smem[ob + (wid * 4 + c) * 512]);
        glds16(Wb + (size_t)(c * 8) * K + k0, &smem[ob + 8192 + (wid * 4 + c) * 512]);
      }
    }
    const int ib = cur * 16384;
    bf16x8 a[4][2], b[4][2];
#pragma unroll
    for (int m = 0; m < 4; ++m)
#pragma unroll
      for (int ks = 0; ks < 2; ++ks)
        a[m][ks] = *reinterpret_cast<const bf16x8*>(
            &smem[ib + (wr * 64 + m * 16 + l15) * 64 + ks * 32 + kg * 8]);
#pragma unroll
    for (int n = 0; n < 4; ++n)
#pragma unroll
      for (int ks = 0; ks < 2; ++ks)
        b[n][ks] = *reinterpret_cast<const bf16x8*>(
            &smem[ib + 8192 + (wc * 64 + n * 16 + l15) * 64 + ks * 32 + kg * 8]);
    __builtin_amdgcn_s_setprio(1);
#pragma unroll
    for (int m = 0; m < 4; ++m)
#pragma unroll
      for (int n = 0; n < 4; ++n)
#pragma unroll
        for (int ks = 0; ks < 2; ++ks)
          acc[m][n] = __builtin_amdgcn_mfma_f32_16x16x32_bf16(a[m][ks], b[n][ks],
                                                              acc[m][n], 0, 0, 0);
    __builtin_amdgcn_s_setprio(0);
    if (t + 1 < nt) {
      asm volatile("s_waitcnt vmcnt(0)" ::: "memory");
      __builtin_amdgcn_s_barrier();
      asm volatile("" ::: "memory");
      cur ^= 1;
    }
  }

  // ---- epilogue: acc -> LDS tile (bf16, stride 137), then norm/rope/transpose ----
  __syncthreads();  // all LDS reads retired before overwrite
#pragma unroll
  for (int m = 0; m < 4; ++m)
#pragma unroll
    for (int n = 0; n < 4; ++n)
#pragma unroll
      for (int r = 0; r < 4; ++r)
        smem[(wr * 64 + m * 16 + kg * 4 + r) * 137 + wc * 64 + n * 16 + l15] =
            f2b(acc[m][n][r]);
  __syncthreads();

  const int ct = blockIdx.x;
  const int b = rowBase >> 11;
  if (ct < 14) {
    const float* nw = (ct < 12) ? q_nw : k_nw;
    const float nwl = nw[lane], nwh = nw[lane + 64];
    const float sc = (ct < 12) ? SCALE_ : 1.0f;
    u16* dstbase = (ct < 12) ? (q_b + (size_t)(b * H_ + ct) * T_ * D_)
                             : (k_b + (size_t)(b * HKV_ + (ct - 12)) * T_ * D_);
    for (int i = 0; i < 32; ++i) {
      const int row = wid * 32 + i;
      const int tok = rowBase + row;
      const int t = tok & (T_ - 1);
      const float x1 = b2f(smem[row * 137 + lane]);
      const float x2 = b2f(smem[row * 137 + lane + 64]);
      float ss = x1 * x1 + x2 * x2;
#pragma unroll
      for (int msk = 32; msk >= 1; msk >>= 1) ss += __shfl_xor(ss, msk);
      const float rinv = rsqrtf(ss * (1.0f / D_) + 1e-6f);
      const float c1 = cosb[(size_t)tok * D_ + lane];
      const float c2 = cosb[(size_t)tok * D_ + lane + 64];
      const float s1 = sinb[(size_t)tok * D_ + lane];
      const float s2 = sinb[(size_t)tok * D_ + lane + 64];
      const float n1 = x1 * rinv * nwl, n2 = x2 * rinv * nwh;
      u16* dst = dstbase + (size_t)t * D_;
      dst[lane] = f2b((n1 * c1 - n2 * s1) * sc);
      dst[lane + 64] = f2b((n2 * c2 + n1 * s2) * sc);
    }
  } else {
    const int hv = ct - 14;
    // kappa^-1 of lane (t&63 == lane by construction: rowBase%64==0)
    const int tp = (lane & 32) | (((lane >> 2) & 3) << 3) | (((lane >> 4) & 1) << 2) |
                   (lane & 3);
    u16* vb = vt_b + (size_t)(b * HKV_ + hv) * D_ * T_;
    const int tb = rowBase & (T_ - 1);
    for (int it = 0; it < 64; ++it) {
      const int d = wid * 32 + (it >> 1), half = it & 1;
      const float x = b2f(smem[(half * 64 + lane) * 137 + d]);
      vb[(size_t)d * T_ + tb + half * 64 + tp] = f2b(x);
    }
  }
}

// ---------------- Flash attention: chunked work items, swapped-QK, kappa-V ----------------
// Round-10 structure (measured best, 72.3us): single-buffer 32KB LDS, no occupancy
// bound (VGPR 144 -> 3 blocks/CU; forcing 4 via launch_bounds spilled to scratch, r11).
__constant__ int QT_ARR[40] = {15,15,15,15,14,14,11,11,11,10, 7, 7, 3,
                               14,14,13,13,13,13,12,12,10,10, 9, 9, 6, 6,
                               12,12, 9, 8, 8, 8, 5, 5, 2,
                                4, 4, 1, 0};
__constant__ int C_ARR[40]  = { 0, 1, 2, 3, 0, 1, 0, 1, 2, 0, 0, 1,-1,
                                2, 3, 0, 1, 2, 3, 0, 1, 1, 2, 0, 1, 0, 1,
                                2, 3, 2, 0, 1, 2, 0, 1,-1,
                                0, 1,-1,-1};
__device__ __forceinline__ int nc_of(int qt) { return (qt < 8) ? 2 : ((qt < 12) ? 3 : 4); }
__device__ __forceinline__ int mlbase_of(int qt) {
  return (qt < 8) ? 2 * (qt - 4) : ((qt < 12) ? 8 + 3 * (qt - 8) : 20 + 4 * (qt - 12));
}
__device__ __forceinline__ int pbase_of(int qt) {
  return (qt < 8) ? (qt - 4) : ((qt < 12) ? 4 + 2 * (qt - 8) : 12 + 3 * (qt - 12));
}

__global__ __launch_bounds__(256) void attn_kernel(const u16* __restrict__ q_b,
                                                   const u16* __restrict__ k_b,
                                                   const u16* __restrict__ vt_b,
                                                   u16* __restrict__ aout,
                                                   u16* __restrict__ po0,
                                                   float2* __restrict__ ml) {
  __shared__ __align__(16) u16 Ks[64 * 128];
  __shared__ __align__(16) u16 Vs[128 * 64];
  const int id = blockIdx.x;        // 0..959, bh fastest
  const int item = id / 24;
  const int bh = id - item * 24;
  const int qt = QT_ARR[item];
  const int c = C_ARR[item];
  int kt0, ktend;
  bool partial;
  if (c < 0) {
    kt0 = 0; ktend = 2 * qt + 1; partial = false;
  } else {
    const int nt = 2 * qt + 2;
    const int nc = nc_of(qt);
    const int base = nt / nc, rem = nt - base * nc;
    kt0 = c * base + (c < rem ? c : rem);
    ktend = kt0 + base + (c < rem ? 1 : 0) - 1;
    partial = true;
  }
  const int b = bh / H_, h = bh - b * H_;
  const int kvh = h / GQ_;
  const int tid = threadIdx.x;
  const int w = tid >> 6, lane = tid & 63;
  const int l15 = lane & 15, kg = lane >> 4;
  const int qbase = qt * 128;

  const u16* Kb = k_b + (size_t)(b * HKV_ + kvh) * T_ * D_;
  const u16* Vb = vt_b + (size_t)(b * HKV_ + kvh) * D_ * T_;

  bf16x8 qf[2][4];
#pragma unroll
  for (int qb = 0; qb < 2; ++qb) {
    const u16* qrow =
        q_b + ((size_t)(b * H_ + h) * T_ + qbase + w * 32 + qb * 16 + l15) * D_;
#pragma unroll
    for (int s4 = 0; s4 < 4; ++s4)
      qf[qb][s4] = *reinterpret_cast<const bf16x8*>(qrow + s4 * 32 + kg * 8);
  }

  int kK[4], vK[4];
#pragma unroll
  for (int cc = 0; cc < 4; ++cc) {
    const int ch = w * 4 + cc;
    const int kr = ch * 4 + (lane >> 4);
    kK[cc] = kr * D_ + (((lane & 15) << 3) ^ ((kr & 7) << 3));
    const int dr = ch * 8 + (lane >> 3);
    vK[cc] = dr * T_ + (((lane & 7) << 3) ^ ((dr & 7) << 3));
  }
  const int xorv = (l15 & 7) << 3;

  const f32x4 zero4 = {0.f, 0.f, 0.f, 0.f};
  f32x4 o[2][8];
#pragma unroll
  for (int qb = 0; qb < 2; ++qb)
#pragma unroll
    for (int n = 0; n < 8; ++n) o[qb][n] = zero4;
  float m[2] = {0.f, 0.f};       // init 0: masked tiles give p=exp(-3e38)=0 safely
  float lsum[2] = {0.f, 0.f};

  for (int kt = kt0; kt <= ktend; ++kt) {
    __syncthreads();  // previous tile fully consumed (WAR)
    {
      const size_t kb = (size_t)kt * 64;
#pragma unroll
      for (int cc = 0; cc < 4; ++cc) {
        glds16(Kb + kb * D_ + kK[cc], &Ks[(w * 4 + cc) * 512]);
        glds16(Vb + kb + vK[cc], &Vs[(w * 4 + cc) * 512]);
      }
    }
    __syncthreads();  // vmcnt(0) drain: tile ready
    f32x4 sc[2][4];
#pragma unroll
    for (int qb = 0; qb < 2; ++qb)
#pragma unroll
      for (int n = 0; n < 4; ++n) sc[qb][n] = zero4;
    __builtin_amdgcn_s_setprio(1);
#pragma unroll
    for (int n = 0; n < 4; ++n)
#pragma unroll
      for (int s4 = 0; s4 < 4; ++s4) {
        const int koff = (n * 16 + l15) * 128 + ((s4 * 32 + kg * 8) ^ xorv);
        bf16x8 kf = *reinterpret_cast<const bf16x8*>(&Ks[koff]);
#pragma unroll
        for (int qb = 0; qb < 2; ++qb)
          sc[qb][n] = __builtin_amdgcn_mfma_f32_16x16x32_bf16(kf, qf[qb][s4],
                                                              sc[qb][n], 0, 0, 0);
      }
    __builtin_amdgcn_s_setprio(0);
    if (kt >= 2 * qt) {  // diagonal region: mask k > q
#pragma unroll
      for (int qb = 0; qb < 2; ++qb) {
        const int qg = w * 32 + qb * 16 + l15;
        const int kbb = (kt - 2 * qt) * 64;
#pragma unroll
        for (int n = 0; n < 4; ++n)
#pragma unroll
          for (int r = 0; r < 4; ++r)
            if (kbb + n * 16 + kg * 4 + r > qg) sc[qb][n][r] = -3e38f;
      }
    }
    float pm[2];
#pragma unroll
    for (int qb = 0; qb < 2; ++qb) {
      float v = sc[qb][0][0];
#pragma unroll
      for (int n = 0; n < 4; ++n)
#pragma unroll
        for (int r = 0; r < 4; ++r) v = fmaxf(v, sc[qb][n][r]);
      v = fmaxf(v, __shfl_xor(v, 16));
      v = fmaxf(v, __shfl_xor(v, 32));
      pm[qb] = v;
    }
    if (__any((pm[0] > m[0] + 8.f) | (pm[1] > m[1] + 8.f))) {
#pragma unroll
      for (int qb = 0; qb < 2; ++qb) {
        const float mn = fmaxf(m[qb], pm[qb]);
        const float al = __expf(m[qb] - mn);
        m[qb] = mn;
        lsum[qb] *= al;
        float alT[4];
#pragma unroll
        for (int r = 0; r < 4; ++r)
          alT[r] = __shfl(al, (lane & 48) | (kg * 4 + r));
#pragma unroll
        for (int n = 0; n < 8; ++n)
#pragma unroll
          for (int r = 0; r < 4; ++r) o[qb][n][r] *= alT[r];
      }
    }
#pragma unroll
    for (int qb = 0; qb < 2; ++qb) {
      float rs = 0.f;
#pragma unroll
      for (int n = 0; n < 4; ++n)
#pragma unroll
        for (int r = 0; r < 4; ++r) {
          const float p = __expf(sc[qb][n][r] - m[qb]);
          sc[qb][n][r] = p;
          rs += p;
        }
      rs += __shfl_xor(rs, 16);
      rs += __shfl_xor(rs, 32);
      lsum[qb] += rs;
    }
    bf16x8 pf[2][2];
#pragma unroll
    for (int qb = 0; qb < 2; ++qb)
#pragma unroll
      for (int ks = 0; ks < 2; ++ks)
#pragma unroll
        for (int r = 0; r < 4; ++r) {
          pf[qb][ks][r] = (short)f2b(sc[qb][2 * ks][r]);
          pf[qb][ks][r + 4] = (short)f2b(sc[qb][2 * ks + 1][r]);
        }
    __builtin_amdgcn_s_setprio(1);
#pragma unroll
    for (int n = 0; n < 8; ++n)
#pragma unroll
      for (int ks = 0; ks < 2; ++ks) {
        const int voff = (n * 16 + l15) * 64 + ((ks * 32 + kg * 8) ^ xorv);
        bf16x8 vf = *reinterpret_cast<const bf16x8*>(&Vs[voff]);
#pragma unroll
        for (int qb = 0; qb < 2; ++qb)
          o[qb][n] = __builtin_amdgcn_mfma_f32_16x16x32_bf16(pf[qb][ks], vf,
                                                             o[qb][n], 0, 0, 0);
      }
    __builtin_amdgcn_s_setprio(0);
  }

  // epilogue: o[qb][n][r] is O[q = qb*16+kg*4+r][d = n*16+l15]
  if (!partial) {
    float invT[2][4];
#pragma unroll
    for (int qb = 0; qb < 2; ++qb) {
      const float inv = 1.0f / lsum[qb];
#pragma unroll
      for (int r = 0; r < 4; ++r)
        invT[qb][r] = __shfl(inv, (lane & 48) | (kg * 4 + r));
    }
#pragma unroll
    for (int qb = 0; qb < 2; ++qb) {
      const int t0 = qbase + w * 32 + qb * 16 + kg * 4;
#pragma unroll
      for (int n = 0; n < 8; ++n)
#pragma unroll
        for (int r = 0; r < 4; ++r)
          aout[(size_t)(b * T_ + t0 + r) * (H_ * D_) + h * D_ + n * 16 + l15] =
              f2b(o[qb][n][r] * invT[qb][r]);
    }
  } else {
    const int mlslot = bh * 36 + mlbase_of(qt) + c;
    if (kg == 0) {
#pragma unroll
      for (int qb = 0; qb < 2; ++qb) {
        float2 v;
        v.x = m[qb];
        v.y = lsum[qb];
        ml[(size_t)mlslot * 128 + w * 32 + qb * 16 + l15] = v;
      }
    }
    if (c == 0) {  // unnormalized partial into this q-tile's aout slot
#pragma unroll
      for (int qb = 0; qb < 2; ++qb) {
        const int t0 = qbase + w * 32 + qb * 16 + kg * 4;
#pragma unroll
        for (int n = 0; n < 8; ++n)
#pragma unroll
          for (int r = 0; r < 4; ++r)
            aout[(size_t)(b * T_ + t0 + r) * (H_ * D_) + h * D_ + n * 16 + l15] =
                f2b(o[qb][n][r]);
      }
    } else {       // unnormalized partial into scratch
      const int pslot = bh * 24 + pbase_of(qt) + (c - 1);
#pragma unroll
      for (int qb = 0; qb < 2; ++qb) {
        const int row0 = w * 32 + qb * 16 + kg * 4;
#pragma unroll
        for (int n = 0; n < 8; ++n)
#pragma unroll
          for (int r = 0; r < 4; ++r)
            po0[((size_t)pslot * 128 + row0 + r) * 128 + n * 16 + l15] =
                f2b(o[qb][n][r]);
      }
    }
  }
}

// ---------------- combine chunked partials (qt >= 4) ----------------
__global__ __launch_bounds__(256) void combine_kernel(u16* __restrict__ aout,
                                                      const u16* __restrict__ po0,
                                                      const float2* __restrict__ ml) {
  const int qt = 4 + blockIdx.x;    // 4..15
  const int bh = blockIdx.y;        // 0..23
  const int nc = nc_of(qt);
  const int mlb = bh * 36 + mlbase_of(qt);
  const int pb = bh * 24 + pbase_of(qt);
  const int b = bh / H_, h = bh - b * H_;
  const int t0 = qt * 128;
  const int tid = threadIdx.x;
  const int row = tid >> 1;
  const int colc = (tid & 1) << 6;

  float ms[4], ls[4];
  float mm = -3e38f;
  for (int cc = 0; cc < nc; ++cc) {
    const float2 v = ml[(size_t)(mlb + cc) * 128 + row];
    ms[cc] = v.x; ls[cc] = v.y;
    mm = fmaxf(mm, v.x);
  }
  float lt = 0.f;
  float scl[4];
  for (int cc = 0; cc < nc; ++cc) {
    scl[cc] = __expf(ms[cc] - mm);
    lt += ls[cc] * scl[cc];
  }
  const float inv = 1.0f / lt;
  for (int cc = 0; cc < nc; ++cc) scl[cc] *= inv;

  u16* a = aout + (size_t)(b * T_ + t0 + row) * (H_ * D_) + h * D_ + colc;
#pragma unroll
  for (int j = 0; j < 8; ++j) {
    u16x8 v0 = *reinterpret_cast<const u16x8*>(a + j * 8);
    float acc[8];
#pragma unroll
    for (int e = 0; e < 8; ++e) acc[e] = b2f(v0[e]) * scl[0];
    for (int cc = 1; cc < nc; ++cc) {
      const u16* p = po0 + ((size_t)(pb + cc - 1) * 128 + row) * 128 + colc;
      u16x8 vc = *reinterpret_cast<const u16x8*>(p + j * 8);
#pragma unroll
      for (int e = 0; e < 8; ++e) acc[e] += b2f(vc[e]) * scl[cc];
    }
    u16x8 outv;
#pragma unroll
    for (int e = 0; e < 8; ++e) outv[e] = f2b(acc[e]);
    *reinterpret_cast<u16x8*>(a + j * 8) = outv;
  }
}

extern "C" void kernel_launch(void* const* d_in, const int* in_sizes, int n_in,
                              void* d_out, int out_size, void* d_ws, size_t ws_size,
                              hipStream_t stream) {
  const float* hidden = (const float*)d_in[0];
  const float* cosb   = (const float*)d_in[1];
  const float* sinb   = (const float*)d_in[2];
  // d_in[3] = attention_mask (pure causal; implemented analytically)
  const float* q_w  = (const float*)d_in[4];
  const float* k_w  = (const float*)d_in[5];
  const float* v_w  = (const float*)d_in[6];
  const float* o_w  = (const float*)d_in[7];
  const float* q_nw = (const float*)d_in[8];
  const float* k_nw = (const float*)d_in[9];
  float* out = (float*)d_out;

  // ws (36MB):
  //   hidden_b [0,12)   phase 1 (dead after gemm_qkv) -> aout [0,12) phase 2
  //   qkvw     [12,18)  phase 1 (dead after gemm_qkv) -> ml [12,13) phase 2
  //   q_b      [18,30)  phase 1+2
  //   owb      [30,34.5) written by cvt_inputs, read by final o-gemm
  // d_out (24MB): k_b [19,21) + vt_b [21,23) (written by gemm_qkv, read by attn);
  //   po0 [0,18.87) attn partials; all overwritten by final o-gemm's fp32 out.
  char* ws = (char*)d_ws;
  const size_t MB = 1u << 20;
  u16*    hidden_b = (u16*)(ws);                   // [0,12)  phase 1
  u16*    qkvw     = (u16*)(ws + 12 * MB);         // [12,18) phase 1
  u16*    q_b      = (u16*)(ws + 18 * MB);         // [18,30)
  u16*    owb      = (u16*)(ws + 30 * MB);         // [30,34.5)
  u16*    aout     = (u16*)(ws);                   // [0,12)  phase 2
  float2* ml       = (float2*)(ws + 12 * MB);      // [12,13) phase 2
  u16*    k_b      = (u16*)((char*)d_out + 19 * MB);  // [19,21) of d_out
  u16*    vt_b     = (u16*)((char*)d_out + 21 * MB);  // [21,23) of d_out
  u16*    po0      = (u16*)d_out;                  // [0,18.87) of d_out

  const dim3 blk(256);
  const int M = B_ * T_;  // 4096

  // merged input converts (hidden, qkv weights, o weight)
  cvt_inputs<<<2048, blk, 0, stream>>>(hidden, q_w, k_w, v_w, o_w,
                                       hidden_b, qkvw, owb);

  // fused QKV projection + RMSNorm + RoPE + V-transpose
  gemm_qkv<<<dim3(NQKV_ / 128, M / 128), blk, 0, stream>>>(
      hidden_b, qkvw, cosb, sinb, q_nw, k_nw, q_b, k_b, vt_b);

  attn_kernel<<<960, blk, 0, stream>>>(q_b, k_b, vt_b, aout, po0, ml);
  combine_kernel<<<dim3(12, B_ * H_), blk, 0, stream>>>(aout, po0, ml);

  // o-projection: 64x128 tile -> 768 blocks = exactly 3/CU (balanced)
  gemm_bt<<<dim3(HID_ / 128, M / 64), blk, 0, stream>>>(aout, owb, out,
                                                        M, HID_, HID_);
}